// Round 1
// baseline (41.779 us; speedup 1.0000x reference)
//
#include <hip/hip_runtime.h>

// Out: (4,64,64,64,32) fp32 = 33,554,432 elems = 8,388,608 float4.
// In:  (4,32,32,32,32) fp32.
// TF1 legacy bilinear (align_corners=False, half_pixel_centers=False):
//   src = dst * (32/64) = dst * 0.5 ; lo = dst>>1 ; hi = min(lo+1, 31) ;
//   frac = 0.5 if dst odd else 0.
__global__ __launch_bounds__(256) void resize3d_kernel(
    const float4* __restrict__ in, float4* __restrict__ out) {
    const int idx = blockIdx.x * 256 + threadIdx.x;   // 0 .. 8388607

    const int c4 = idx & 7;           // float4 index along C (C=32 -> 8)
    const int ow = (idx >> 3) & 63;
    const int oh = (idx >> 9) & 63;
    const int od = (idx >> 15) & 63;
    const int b  = idx >> 21;         // 0..3

    const int d0 = od >> 1, h0 = oh >> 1, w0 = ow >> 1;
    const int d1 = min(d0 + 1, 31);
    const int h1 = min(h0 + 1, 31);
    const int w1 = min(w0 + 1, 31);
    const float fd = (od & 1) ? 0.5f : 0.0f;
    const float fh = (oh & 1) ? 0.5f : 0.0f;
    const float fw = (ow & 1) ? 0.5f : 0.0f;

    // input voxel offset in float4 units: (((b*32+d)*32+h)*32+w)*8 + c4
    const float4* inb = in + ((size_t)b << 18) + c4;
#define VIDX(d, h, w) (((d) << 13) + ((h) << 8) + ((w) << 3))
    float4 v000 = inb[VIDX(d0, h0, w0)];
    float4 v001 = inb[VIDX(d0, h0, w1)];
    float4 v010 = inb[VIDX(d0, h1, w0)];
    float4 v011 = inb[VIDX(d0, h1, w1)];
    float4 v100 = inb[VIDX(d1, h0, w0)];
    float4 v101 = inb[VIDX(d1, h0, w1)];
    float4 v110 = inb[VIDX(d1, h1, w0)];
    float4 v111 = inb[VIDX(d1, h1, w1)];
#undef VIDX

    // lerp along D first, then H, then W (matches reference axis order)
#define LERP4(a, b, f)                                     \
    make_float4(a.x + (b.x - a.x) * (f),                   \
                a.y + (b.y - a.y) * (f),                   \
                a.z + (b.z - a.z) * (f),                   \
                a.w + (b.w - a.w) * (f))
    float4 v00 = LERP4(v000, v100, fd);
    float4 v01 = LERP4(v001, v101, fd);
    float4 v10 = LERP4(v010, v110, fd);
    float4 v11 = LERP4(v011, v111, fd);
    float4 v0  = LERP4(v00, v10, fh);
    float4 v1  = LERP4(v01, v11, fh);
    float4 r   = LERP4(v0, v1, fw);
#undef LERP4

    out[idx] = r;
}

extern "C" void kernel_launch(void* const* d_in, const int* in_sizes, int n_in,
                              void* d_out, int out_size, void* d_ws, size_t ws_size,
                              hipStream_t stream) {
    const float4* in = (const float4*)d_in[0];
    float4* out = (float4*)d_out;
    const int n4 = out_size / 4;              // 8,388,608
    const int grid = n4 / 256;                // 32,768 blocks, no tail
    resize3d_kernel<<<grid, 256, 0, stream>>>(in, out);
}

// Round 2
// 30.014 us; speedup vs baseline: 1.3920x; 1.3920x over previous
//
#include <hip/hip_runtime.h>

// Out: (4,64,64,64,32) fp32. In: (4,32,32,32,32) fp32. Pure 2x trilinear
// upsample, TF1 legacy mapping: src = dst*0.5, frac in {0, 0.5},
// hi = min(lo+1, 31).
//
// Block scheme: one thread owns one input base voxel (b,d0,h0,w0) and one
// float4 lane c4 along C; it loads the 8 corners once and writes the full
// 2x2x2 output block -> 1 load + 1 store per output float4 (R1 was 8+1,
// L1/VMEM-pipe bound).
__global__ __launch_bounds__(256) void resize3d_up2(
    const float4* __restrict__ in, float4* __restrict__ out) {
    const int idx = blockIdx.x * 256 + threadIdx.x;   // 0 .. 1,048,575

    const int c4 = idx & 7;            // float4 index along C
    const int w0 = (idx >> 3) & 31;
    const int h0 = (idx >> 8) & 31;
    const int d0 = (idx >> 13) & 31;
    const int b  = idx >> 18;          // 0..3

    const int d1 = min(d0 + 1, 31);
    const int h1 = min(h0 + 1, 31);
    const int w1 = min(w0 + 1, 31);

    // input float4 offset: (((b*32+d)*32+h)*32+w)*8 + c4
    const float4* inb = in + ((size_t)b << 18) + c4;
#define VIDX(d, h, w) (((d) << 13) + ((h) << 8) + ((w) << 3))
    float4 v000 = inb[VIDX(d0, h0, w0)];
    float4 v001 = inb[VIDX(d0, h0, w1)];
    float4 v010 = inb[VIDX(d0, h1, w0)];
    float4 v011 = inb[VIDX(d0, h1, w1)];
    float4 v100 = inb[VIDX(d1, h0, w0)];
    float4 v101 = inb[VIDX(d1, h0, w1)];
    float4 v110 = inb[VIDX(d1, h1, w0)];
    float4 v111 = inb[VIDX(d1, h1, w1)];
#undef VIDX

    // lerp a + (b-a)*0.5 in D,H,W order — bit-exact vs reference
#define LERP4(a, b)                                        \
    make_float4(a.x + (b.x - a.x) * 0.5f,                  \
                a.y + (b.y - a.y) * 0.5f,                  \
                a.z + (b.z - a.z) * 0.5f,                  \
                a.w + (b.w - a.w) * 0.5f)

    // D-midplane corners (rd = 1)
    float4 q00 = LERP4(v000, v100);
    float4 q01 = LERP4(v001, v101);
    float4 q10 = LERP4(v010, v110);
    float4 q11 = LERP4(v011, v111);

    // output float4 offset: (b<<21) + (od<<15) + (oh<<9) + (ow<<3) + c4,
    // od = 2*d0 + rd etc.
    float4* outb = out + ((size_t)b << 21) + (d0 << 16) + (h0 << 10) +
                   (w0 << 4) + c4;

#define EMIT_PLANE(p00, p01, p10, p11, off)                \
    do {                                                   \
        float4 eh = LERP4(p00, p10);        /* rh=1,rw=0 */\
        float4 eh2 = LERP4(p01, p11);                      \
        outb[(off) + 0]   = p00;            /* rh=0,rw=0 */\
        outb[(off) + 8]   = LERP4(p00, p01);/* rh=0,rw=1 */\
        outb[(off) + 512] = eh;                            \
        outb[(off) + 520] = LERP4(eh, eh2); /* rh=1,rw=1 */\
    } while (0)

    EMIT_PLANE(v000, v001, v010, v011, 0);       // rd = 0
    EMIT_PLANE(q00, q01, q10, q11, 32768);       // rd = 1
#undef EMIT_PLANE
#undef LERP4
}

extern "C" void kernel_launch(void* const* d_in, const int* in_sizes, int n_in,
                              void* d_out, int out_size, void* d_ws, size_t ws_size,
                              hipStream_t stream) {
    const float4* in = (const float4*)d_in[0];
    float4* out = (float4*)d_out;
    const int threads = out_size / 32;        // 1,048,576 (8 outputs/thread)
    const int grid = threads / 256;           // 4096 blocks, no tail
    resize3d_up2<<<grid, 256, 0, stream>>>(in, out);
}

// Round 4
// 29.377 us; speedup vs baseline: 1.4222x; 1.0217x over previous
//
#include <hip/hip_runtime.h>

// Out: (4,64,64,64,32) fp32. In: (4,32,32,32,32) fp32. Pure 2x trilinear
// upsample, TF1 legacy mapping: src = dst*0.5, frac in {0, 0.5},
// hi = min(lo+1, 31).
//
// One thread = one input base voxel (b,d0,h0,w0) x one float4 lane c4;
// loads the 8 corners, writes the 2x2x2 output block (8 float4 stores).
// R4 = R3 retry: non-temporal stores via native ext_vector_type (the HIP
// float4 struct is rejected by __builtin_nontemporal_store).
typedef float floatx4 __attribute__((ext_vector_type(4)));

__global__ __launch_bounds__(256) void resize3d_up2(
    const floatx4* __restrict__ in, floatx4* __restrict__ out) {
    const int idx = blockIdx.x * 256 + threadIdx.x;   // 0 .. 1,048,575

    const int c4 = idx & 7;            // float4 index along C
    const int w0 = (idx >> 3) & 31;
    const int h0 = (idx >> 8) & 31;
    const int d0 = (idx >> 13) & 31;
    const int b  = idx >> 18;          // 0..3

    const int d1 = min(d0 + 1, 31);
    const int h1 = min(h0 + 1, 31);
    const int w1 = min(w0 + 1, 31);

    // input float4 offset: (((b*32+d)*32+h)*32+w)*8 + c4
    const floatx4* inb = in + ((size_t)b << 18) + c4;
#define VIDX(d, h, w) (((d) << 13) + ((h) << 8) + ((w) << 3))
    floatx4 v000 = inb[VIDX(d0, h0, w0)];
    floatx4 v001 = inb[VIDX(d0, h0, w1)];
    floatx4 v010 = inb[VIDX(d0, h1, w0)];
    floatx4 v011 = inb[VIDX(d0, h1, w1)];
    floatx4 v100 = inb[VIDX(d1, h0, w0)];
    floatx4 v101 = inb[VIDX(d1, h0, w1)];
    floatx4 v110 = inb[VIDX(d1, h1, w0)];
    floatx4 v111 = inb[VIDX(d1, h1, w1)];
#undef VIDX

    // lerp a + (b-a)*0.5 in D,H,W order — bit-exact vs reference
#define LERP4(a, b) ((a) + ((b) - (a)) * 0.5f)

    // D-midplane corners (rd = 1)
    floatx4 q00 = LERP4(v000, v100);
    floatx4 q01 = LERP4(v001, v101);
    floatx4 q10 = LERP4(v010, v110);
    floatx4 q11 = LERP4(v011, v111);

    // output float4 offset: (b<<21) + (od<<15) + (oh<<9) + (ow<<3) + c4,
    // od = 2*d0 + rd etc.
    floatx4* outb = out + ((size_t)b << 21) + (d0 << 16) + (h0 << 10) +
                    (w0 << 4) + c4;

#define NTST(p, v) __builtin_nontemporal_store((v), (p))
#define EMIT_PLANE(p00, p01, p10, p11, off)                 \
    do {                                                    \
        floatx4 eh  = LERP4(p00, p10);       /* rh=1,rw=0 */\
        floatx4 eh2 = LERP4(p01, p11);                      \
        NTST(outb + (off) + 0,   p00);       /* rh=0,rw=0 */\
        NTST(outb + (off) + 8,   LERP4(p00, p01));          \
        NTST(outb + (off) + 512, eh);                       \
        NTST(outb + (off) + 520, LERP4(eh, eh2));           \
    } while (0)

    EMIT_PLANE(v000, v001, v010, v011, 0);       // rd = 0
    EMIT_PLANE(q00, q01, q10, q11, 32768);       // rd = 1
#undef EMIT_PLANE
#undef NTST
#undef LERP4
}

extern "C" void kernel_launch(void* const* d_in, const int* in_sizes, int n_in,
                              void* d_out, int out_size, void* d_ws, size_t ws_size,
                              hipStream_t stream) {
    const floatx4* in = (const floatx4*)d_in[0];
    floatx4* out = (floatx4*)d_out;
    const int threads = out_size / 32;        // 1,048,576 (8 outputs/thread)
    const int grid = threads / 256;           // 4096 blocks, no tail
    resize3d_up2<<<grid, 256, 0, stream>>>(in, out);
}

// Round 5
// 28.768 us; speedup vs baseline: 1.4523x; 1.0212x over previous
//
#include <hip/hip_runtime.h>

// Out: (4,64,64,64,32) fp32. In: (4,32,32,32,32) fp32. Pure 2x trilinear
// upsample, TF1 legacy mapping: src = dst*0.5, frac in {0,0.5}, hi=min(lo+1,31).
//
// R5: d-rolling loop. One thread owns (b, d-group of 2, h0, w0, c4); it keeps
// the current input d-plane's 4 corners in registers and loads only the next
// plane per iteration: 12 loads / 16 float4 outputs (was 16/16). Grid = 2048
// blocks = exactly one residency round (8 blocks/CU). NT stores kept from R4.
typedef float floatx4 __attribute__((ext_vector_type(4)));

__global__ __launch_bounds__(256) void resize3d_up2(
    const floatx4* __restrict__ in, floatx4* __restrict__ out) {
    const int tid = threadIdx.x;        // 256 = 32 w0 x 8 c4
    const int c4 = tid & 7;
    const int w0 = tid >> 3;            // 0..31
    const int bid = blockIdx.x;         // 0..2047 = b(2) | dg(4) | h0(5)
    const int h0 = bid & 31;
    const int dg = (bid >> 5) & 15;     // group of 2 d-planes
    const int b  = bid >> 9;            // 0..3

    const int h1 = min(h0 + 1, 31);
    const int w1 = min(w0 + 1, 31);
    const int d0 = dg << 1;

    // input float4 offset: (((b*32+d)*32+h)*32+w)*8 + c4
    const floatx4* inb = in + ((size_t)b << 18) + c4;
#define VIDX(d, h, w) (((d) << 13) + ((h) << 8) + ((w) << 3))
    floatx4 c00 = inb[VIDX(d0, h0, w0)];
    floatx4 c01 = inb[VIDX(d0, h0, w1)];
    floatx4 c10 = inb[VIDX(d0, h1, w0)];
    floatx4 c11 = inb[VIDX(d0, h1, w1)];

    // output float4 offset: (b<<21) + (od<<15) + (oh<<9) + (ow<<3) + c4,
    // oh = 2*h0, ow = 2*w0
    floatx4* outb0 = out + ((size_t)b << 21) + (h0 << 10) + (w0 << 4) + c4;

#define LERP4(a, b) ((a) + ((b) - (a)) * 0.5f)
#define NTST(p, v) __builtin_nontemporal_store((v), (p))
#define EMIT_PLANE(p00, p01, p10, p11, base)                \
    do {                                                    \
        floatx4 eh  = LERP4(p00, p10);       /* rh=1,rw=0 */\
        floatx4 eh2 = LERP4(p01, p11);                      \
        NTST((base) + 0,   p00);             /* rh=0,rw=0 */\
        NTST((base) + 8,   LERP4(p00, p01)); /* rh=0,rw=1 */\
        NTST((base) + 512, eh);                             \
        NTST((base) + 520, LERP4(eh, eh2));  /* rh=1,rw=1 */\
    } while (0)

#pragma unroll
    for (int it = 0; it < 2; ++it) {
        const int d  = d0 + it;
        const int dn = min(d + 1, 31);
        floatx4 n00 = inb[VIDX(dn, h0, w0)];
        floatx4 n01 = inb[VIDX(dn, h0, w1)];
        floatx4 n10 = inb[VIDX(dn, h1, w0)];
        floatx4 n11 = inb[VIDX(dn, h1, w1)];

        // D-midplane corners (od = 2d+1, frac 0.5)
        floatx4 q00 = LERP4(c00, n00);
        floatx4 q01 = LERP4(c01, n01);
        floatx4 q10 = LERP4(c10, n10);
        floatx4 q11 = LERP4(c11, n11);

        floatx4* ob = outb0 + ((size_t)d << 16);   // od = 2d plane
        EMIT_PLANE(c00, c01, c10, c11, ob);        // rd = 0
        EMIT_PLANE(q00, q01, q10, q11, ob + 32768);// rd = 1

        c00 = n00; c01 = n01; c10 = n10; c11 = n11;
    }
#undef EMIT_PLANE
#undef NTST
#undef LERP4
#undef VIDX
}

extern "C" void kernel_launch(void* const* d_in, const int* in_sizes, int n_in,
                              void* d_out, int out_size, void* d_ws, size_t ws_size,
                              hipStream_t stream) {
    const floatx4* in = (const floatx4*)d_in[0];
    floatx4* out = (floatx4*)d_out;
    // 16 float4 outputs per thread, 256 threads per block
    const int grid = out_size / (4 * 16 * 256);   // 2048 blocks, no tail
    resize3d_up2<<<grid, 256, 0, stream>>>(in, out);
}